// Round 1
// 256.639 us; speedup vs baseline: 1.0537x; 1.0537x over previous
//
#include <hip/hip_runtime.h>
#include <cmath>

// Problem constants from the reference: x is (16, 1, 1536, 1536) float32.
#define B_ 16
#define H_ 1536
#define W_ 1536

typedef float v4f __attribute__((ext_vector_type(4)));

// NUMERICS CONTRACT (revised from the all-IEEE version, same guarantees):
// the sign of disc = Hc^2 - Kc is rounding-determined and selects between
// si=0 (NaN path) and si~=+-1 -- a jump of 1.0. The reference association
// and rounding must therefore be reproduced EXACTLY wherever that sign is
// in doubt. New structure:
//  * FRONT-END (p,q,r,s,t,one_pq,A,sq,cube,numk): unchanged, contract(off),
//    reference order -- feeds both paths, must stay bitwise.
//  * FAST PATH (all lanes): Hc = -A*rcp(2*sqrt_raw(cube)),
//    Kc = numk*rcp(sq) with raw v_sqrt_f32/v_rcp_f32 (<=1 ulp each).
//    Error bound vs the IEEE reference values:
//      |disc_fast - disc_ieee| <= ~17ulp*(Hc^2+|Kc|) ~= 2^-20 * mag.
//  * GUARD: lanes with |disc_fast| <= 2^-16 * (Hc^2+|Kc|)  (16x margin over
//    the bound) are recomputed with IEEE div/sqrt, reproducing the
//    reference disc bitwise. So the disc SIGN always matches the reference.
//    Unflagged lanes: |disc| > 2^-16*mag implies z = num/den is either
//    accurate to ~ulp (disc ~ mag) or saturated (|z| >~ 90 near the
//    threshold), so the <=6% worst-case disc perturbation at the guard
//    edge moves si by < 1e-4 -- inside tolerance.
//  * root = sqrt_raw(disc) for ALL lanes: by the same saturation argument a
//    1-ulp root error moves si by ~1e-7; disc<0 -> NaN -> si=0 either way.
//    (disc itself is sign-exact per the guard, which is all that matters.)
// Expected slow-path rate ~1e-5 of elements -> <1% of waves diverge.
//
// Dropped-check justifications (output-equivalent for finite inputs):
//  * remove_nan(Hc): denom 2*sqrt(cube) >= 2 (one_pq >= 1), A finite
//    for N(0,1) inputs -> Hc never NaN (rcp/sqrt args >= 1: no denormal,
//    no inf).
//  * remove_nan(Kc): denom sq >= 1, numerator finite -> never NaN.
//  * remove_nan(kmin/kmax): NaN iff root is NaN; reference then yields
//    num=den=0 -> z=NaN -> si=0; propagating the NaN yields z=NaN -> si=0.
__global__ __launch_bounds__(384) void ShapeIndex_kernel(
        const float* __restrict__ x, float* __restrict__ out) {
#pragma clang fp contract(off)
    // XCD-chunked h swizzle: grid.x=1536 (divisible by 8 XCDs), so the
    // hardware round-robin gives XCD k the blocks with hraw%8==k. Remap so
    // each XCD walks a contiguous 192-row band -> the 3-row stencil
    // re-reads hit that XCD's own L2 instead of re-fetching (FETCH_SIZE
    // was 1.5x ideal). Bijection on [0,1536): full coverage preserved.
    const int hraw = blockIdx.x;
    const int h  = (hraw & 7) * (H_ / 8) + (hraw >> 3);
    const int b  = blockIdx.y;       // 0..15
    const int w  = threadIdx.x * 4;

    const float* plane = x + (size_t)b * (H_ * W_);
    const int hm1 = (h == 0) ? (H_ - 1) : (h - 1);
    const int hm2 = (h <= 1) ? (h + H_ - 2) : (h - 2);

    const float4 vc = *(const float4*)(plane + h   * W_ + w);  // x[h][w..w+3]
    const float4 v1 = *(const float4*)(plane + hm1 * W_ + w);  // x[h-1][...]
    const float4 v2 = *(const float4*)(plane + hm2 * W_ + w);  // x[h-2][...]

    const int wm1 = (w == 0) ? (W_ - 1) : (w - 1);
    const int wm2 = (w == 0) ? (W_ - 2) : (w - 2);
    const float L0  = plane[h   * W_ + wm1];  // x[h][w-1]
    const float L1  = plane[h   * W_ + wm2];  // x[h][w-2]
    const float Lh1 = plane[hm1 * W_ + wm1];  // x[h-1][w-1]

    const v4f xc    = {vc.x, vc.y, vc.z, vc.w};
    const v4f xh1   = {v1.x, v1.y, v1.z, v1.w};
    const v4f xh2   = {v2.x, v2.y, v2.z, v2.w};
    const v4f xw1   = {L0,  vc.x, vc.y, vc.z};   // x[h][w-1] per element
    const v4f xw2   = {L1,  L0,  vc.x, vc.y};    // x[h][w-2] per element
    const v4f xh1w1 = {Lh1, v1.x, v1.y, v1.z};   // x[h-1][w-1] per element

    // grad(m, ax) = roll(m,1,ax) - m : single f32 subs, reference order.
    const v4f p    = xh1   - xc;
    const v4f q    = xw1   - xc;
    const v4f p_up = xh2   - xh1;
    const v4f p_lf = xh1w1 - xw1;
    const v4f q_lf = xw2   - xw1;
    const v4f r = p_up - p;
    const v4f s = p_lf - p;
    const v4f t = q_lf - q;

    const v4f pp = p * p;
    const v4f qq = q * q;
    const v4f one_pq = (1.0f + pp) + qq;               // (1.0 + p*p) + q*q
    // ((1+q*q)*r - 2.0*p*q*s) + (1+p*p)*t, left-to-right like Python
    const v4f A = ((1.0f + qq) * r - ((2.0f * p) * q) * s) + (1.0f + pp) * t;
    const v4f sq   = one_pq * one_pq;                  // one_pq ** 2
    const v4f cube = sq * one_pq;                      // one_pq ** 3
    const v4f numk = r * t - s * s;

    // ---- FAST PATH: raw-rate sqrt/rcp (<=1 ulp). args >= 1, no specials.
    v4f Hc, Kc;
#pragma unroll
    for (int j = 0; j < 4; ++j) {
        const float sr = __builtin_amdgcn_sqrtf(cube[j]);      // raw v_sqrt
        Hc[j] = -A[j] * __builtin_amdgcn_rcpf(sr + sr);        // ~ -A/(2*sqrt)
        Kc[j] = numk[j] * __builtin_amdgcn_rcpf(sq[j]);        // ~ numk/sq
    }
    const v4f HH = Hc * Hc;
    v4f disc = HH - Kc;                                // sign is critical

    // ---- GUARD: route sign-ambiguous lanes to the bitwise-exact path.
    v4f mag;
#pragma unroll
    for (int j = 0; j < 4; ++j) mag[j] = HH[j] + __builtin_fabsf(Kc[j]);
    const v4f thr = mag * 0x1p-16f;
    bool need[4];
    bool any = false;
#pragma unroll
    for (int j = 0; j < 4; ++j) {
        need[j] = __builtin_fabsf(disc[j]) <= thr[j];  // mag==0 -> flagged
        any |= need[j];
    }
    if (__builtin_expect(any, 0)) {
#pragma unroll
        for (int j = 0; j < 4; ++j) if (need[j]) {
            // Exact reference association: IEEE sqrt + IEEE div, mul-then-sub.
            const float se  = __builtin_sqrtf(cube[j]);        // IEEE 0.5ulp
            const float hce = -(A[j] / (2.0f * se));           // IEEE div
            const float kce = numk[j] / sq[j];                 // IEEE div
            Hc[j]   = hce;
            Kc[j]   = kce;
            disc[j] = hce * hce - kce;                         // bitwise ref
        }
    }

    // root: raw sqrt is enough for ALL lanes -- disc sign already exact,
    // and si is saturation-insensitive to ~ulp root error (see contract).
    v4f root;
#pragma unroll
    for (int j = 0; j < 4; ++j) root[j] = __builtin_amdgcn_sqrtf(disc[j]); // NaN if <0

    const v4f kmin = Hc - root;   // NaN propagates (equivalent to ref, see top)
    const v4f kmax = Hc + root;
    const v4f num  = kmax + kmin;
    const v4f den  = kmax - kmin;

    // z = num/den via num*rcp(den): den=0 -> +-inf (num!=0) or NaN (num==0);
    // NaN den -> NaN. Matches IEEE special cases; ~1ulp finite error lands in
    // atan's smooth/saturating region (verified: absmax identical to libm).
    v4f z;
#pragma unroll
    for (int j = 0; j < 4; ++j) z[j] = num[j] * __builtin_amdgcn_rcpf(den[j]);

    // fast atan, ~1e-5 rad: atan(x)=pi/2-atan(1/x) for |x|>1; rcp(inf)=0
    // gives exact +-pi/2 saturation; NaN>1 false -> NaN propagates via poly.
    v4f u;
    bool big[4];
#pragma unroll
    for (int j = 0; j < 4; ++j) {
        const float az  = __builtin_fabsf(z[j]);
        const float inv = __builtin_amdgcn_rcpf(az);
        big[j] = az > 1.0f;
        u[j]   = big[j] ? inv : az;
    }
    const v4f x2 = u * u;
    const v4f C5 = -0.01172120f, C4 = 0.05265332f, C3 = -0.11643287f,
              C2 = 0.19354346f,  C1 = -0.33262347f, C0 = 0.99997726f;
    v4f pl = __builtin_elementwise_fma(x2, C5, C4);
    pl = __builtin_elementwise_fma(x2, pl, C3);
    pl = __builtin_elementwise_fma(x2, pl, C2);
    pl = __builtin_elementwise_fma(x2, pl, C1);
    pl = __builtin_elementwise_fma(x2, pl, C0);
    const v4f a    = u * pl;
    const v4f asub = 1.57079632679489662f - a;

    v4f rs;
#pragma unroll
    for (int j = 0; j < 4; ++j)
        rs[j] = __builtin_copysignf(big[j] ? asub[j] : a[j], z[j]);
    const v4f siv = 0.63661977236758134f * rs;

    float res[4];
#pragma unroll
    for (int j = 0; j < 4; ++j)
        res[j] = (siv[j] == siv[j]) ? siv[j] : 0.0f;   // remove_nan

    *(float4*)(out + (size_t)b * (H_ * W_) + h * W_ + w) =
        make_float4(res[0], res[1], res[2], res[3]);
}

extern "C" void kernel_launch(void* const* d_in, const int* in_sizes, int n_in,
                              void* d_out, int out_size, void* d_ws, size_t ws_size,
                              hipStream_t stream) {
    const float* x = (const float*)d_in[0];
    float* out = (float*)d_out;
    dim3 grid(H_, B_);
    dim3 block(384);
    ShapeIndex_kernel<<<grid, block, 0, stream>>>(x, out);
}

// Round 2
// 255.846 us; speedup vs baseline: 1.0570x; 1.0031x over previous
//
#include <hip/hip_runtime.h>
#include <cmath>

// Problem constants from the reference: x is (16, 1, 1536, 1536) float32.
#define B_ 16
#define H_ 1536
#define W_ 1536

typedef float v4f __attribute__((ext_vector_type(4)));

// NUMERICS CONTRACT (v3 -- same guarantees as v2, fewer ops):
// the sign of disc = Hc^2 - Kc is rounding-determined and selects between
// si=0 (NaN path) and si~=+-1 -- a jump of 1.0. The reference association
// and rounding are reproduced EXACTLY wherever that sign is in doubt.
//  * FRONT-END (p,q,r,s,t,one_pq,A,numk): contract(off), reference order --
//    feeds both paths, must stay bitwise.
//  * FAST PATH (all lanes): one rsq per element replaces sqrt+2 divides:
//      r1 = rsq(one_pq); Hc = (-0.5*A)*(r1^3); Kc = numk*(r1^4).
//    Error vs IEEE reference: |d(Hc)|<=~7ulp, |d(Kc)|<=~8ulp ->
//    |disc_fast - disc_ieee| <= ~2^-20 * (Hc^2+|Kc|).
//  * GUARD: lanes with |disc_fast| <= 2^-16 * (Hc^2+|Kc|) (16x margin) are
//    recomputed with IEEE div/sqrt in reference association -> disc SIGN
//    always matches the reference bitwise. Unflagged lanes: z is either
//    ~ulp-accurate or saturated (|z|>~256 at the guard edge), so the
//    worst-case disc perturbation moves si by < 1e-4 -- inside tolerance.
//  * TAIL: z = num/den with num=kmax+kmin, den=kmax-kmin collapses to
//    z = Hc/root (den = 2*root >= +0 always, so sign(z) = sign(Hc); the
//    reference's rounded num/den differ from 2Hc/2root by ~1ulp, moving
//    si by ~1e-7). atan uses u = mn/mx of (|Hc|, root) -- one rcp instead
//    of rcp(den) + rcp(|z|). mn/mx are built with cndmask on (|Hc|>root),
//    NOT v_min/v_max: a NaN root (disc<0) then lands in mx -> u=NaN ->
//    poly NaN -> si=0, exactly the reference's remove_nan cascade
//    (kmin/kmax->0 -> z=0/0=NaN -> si=0). root uses raw v_sqrt for all
//    lanes: disc sign is already exact and si is saturation-insensitive
//    to ~ulp root error. Special cases checked: root=0 & Hc!=0 -> u=0,
//    big -> si=+-1 (ref: z=2Hc/+0=+-inf); root=0 & Hc=0 -> u=0*inf=NaN
//    -> si=0 (ref: z=0/0); u<=1+ulp always, poly(1)<pi/2 so asub>0.
//
// Dropped-check justifications (output-equivalent for finite inputs):
//  * remove_nan(Hc): one_pq >= 1 -> rsq arg >= 1, A finite -> Hc finite.
//  * remove_nan(Kc): r1^4 <= 1, numk finite -> Kc finite.
//  * remove_nan(kmin/kmax): handled by the NaN-propagating cndmask tail
//    (see TAIL above).
__global__ __launch_bounds__(384) void ShapeIndex_kernel(
        const float* __restrict__ x, float* __restrict__ out) {
#pragma clang fp contract(off)
    // XCD-chunked h swizzle: grid.x=1536 (divisible by 8 XCDs); remap so
    // each XCD walks a contiguous 192-row band -> stencil re-reads hit the
    // home XCD's L2. Bijection on [0,1536).
    const int hraw = blockIdx.x;
    const int h  = (hraw & 7) * (H_ / 8) + (hraw >> 3);
    const int b  = blockIdx.y;       // 0..15
    const int w  = threadIdx.x * 4;

    const float* plane = x + (size_t)b * (H_ * W_);
    const int hm1 = (h == 0) ? (H_ - 1) : (h - 1);
    const int hm2 = (h <= 1) ? (h + H_ - 2) : (h - 2);

    const float4 vc = *(const float4*)(plane + h   * W_ + w);  // x[h][w..w+3]
    const float4 v1 = *(const float4*)(plane + hm1 * W_ + w);  // x[h-1][...]
    const float4 v2 = *(const float4*)(plane + hm2 * W_ + w);  // x[h-2][...]

    const int wm1 = (w == 0) ? (W_ - 1) : (w - 1);
    const int wm2 = (w == 0) ? (W_ - 2) : (w - 2);
    const float L0  = plane[h   * W_ + wm1];  // x[h][w-1]
    const float L1  = plane[h   * W_ + wm2];  // x[h][w-2]
    const float Lh1 = plane[hm1 * W_ + wm1];  // x[h-1][w-1]

    const v4f xc    = {vc.x, vc.y, vc.z, vc.w};
    const v4f xh1   = {v1.x, v1.y, v1.z, v1.w};
    const v4f xh2   = {v2.x, v2.y, v2.z, v2.w};
    const v4f xw1   = {L0,  vc.x, vc.y, vc.z};   // x[h][w-1] per element
    const v4f xw2   = {L1,  L0,  vc.x, vc.y};    // x[h][w-2] per element
    const v4f xh1w1 = {Lh1, v1.x, v1.y, v1.z};   // x[h-1][w-1] per element

    // grad(m, ax) = roll(m,1,ax) - m : single f32 subs, reference order.
    const v4f p    = xh1   - xc;
    const v4f q    = xw1   - xc;
    const v4f p_up = xh2   - xh1;
    const v4f p_lf = xh1w1 - xw1;
    const v4f q_lf = xw2   - xw1;
    const v4f r = p_up - p;
    const v4f s = p_lf - p;
    const v4f t = q_lf - q;

    const v4f pp = p * p;
    const v4f qq = q * q;
    const v4f one_pq = (1.0f + pp) + qq;               // (1.0 + p*p) + q*q
    // ((1+q*q)*r - 2.0*p*q*s) + (1+p*p)*t, left-to-right like Python
    const v4f A = ((1.0f + qq) * r - ((2.0f * p) * q) * s) + (1.0f + pp) * t;
    const v4f numk = r * t - s * s;

    // ---- FAST PATH: one rsq per element; powers give both denominators.
    v4f rsqv;
#pragma unroll
    for (int j = 0; j < 4; ++j)
        rsqv[j] = __builtin_amdgcn_rsqf(one_pq[j]);    // one_pq^-1/2, ~1ulp
    const v4f i2 = rsqv * rsqv;                        // ~ one_pq^-1
    const v4f i3 = i2 * rsqv;                          // ~ one_pq^-3/2
    const v4f i4 = i2 * i2;                            // ~ one_pq^-2
    const v4f halfA = -0.5f * A;
    v4f Hc = halfA * i3;                               // ~ -A/(2*sqrt(cube))
    v4f Kc = numk * i4;                                // ~ numk/sq
    const v4f HH = Hc * Hc;
    v4f disc = HH - Kc;                                // sign is critical

    // ---- GUARD: route sign-ambiguous lanes to the bitwise-exact path.
    v4f mag;
#pragma unroll
    for (int j = 0; j < 4; ++j) mag[j] = HH[j] + __builtin_fabsf(Kc[j]);
    const v4f thr = mag * 0x1p-16f;
    bool need[4];
    bool any = false;
#pragma unroll
    for (int j = 0; j < 4; ++j) {
        need[j] = __builtin_fabsf(disc[j]) <= thr[j];  // mag==0 -> flagged
        any |= need[j];
    }
    if (__builtin_expect(any, 0)) {
#pragma unroll
        for (int j = 0; j < 4; ++j) if (need[j]) {
            // Exact reference association: IEEE sqrt + IEEE div, mul-then-sub.
            const float sqj  = one_pq[j] * one_pq[j];          // one_pq ** 2
            const float cubj = sqj * one_pq[j];                // one_pq ** 3
            const float se  = __builtin_sqrtf(cubj);           // IEEE 0.5ulp
            const float hce = -(A[j] / (2.0f * se));           // IEEE div
            const float kce = numk[j] / sqj;                   // IEEE div
            Hc[j]   = hce;
            disc[j] = hce * hce - kce;                         // bitwise ref
        }
    }

    // root: raw sqrt for ALL lanes -- disc sign already exact; disc<0 -> NaN.
    v4f root;
#pragma unroll
    for (int j = 0; j < 4; ++j) root[j] = __builtin_amdgcn_sqrtf(disc[j]);

    // atan argument u = mn/mx of (|Hc|, root); sign carried by Hc.
    // cndmask (not min/max) so NaN root -> mx=NaN -> u=NaN -> si=0.
    v4f u;
    bool big[4];
#pragma unroll
    for (int j = 0; j < 4; ++j) {
        const float aH = __builtin_fabsf(Hc[j]);
        big[j] = aH > root[j];                  // NaN compares false
        const float mn = big[j] ? root[j] : aH;
        const float mx = big[j] ? aH : root[j];
        u[j] = mn * __builtin_amdgcn_rcpf(mx);  // mx=0 -> 0*inf=NaN (ref: 0/0)
    }

    // fast atan, ~1e-5 rad: atan(x)=pi/2-atan(1/x) for the big branch.
    const v4f x2 = u * u;
    const v4f C5 = -0.01172120f, C4 = 0.05265332f, C3 = -0.11643287f,
              C2 = 0.19354346f,  C1 = -0.33262347f, C0 = 0.99997726f;
    v4f pl = __builtin_elementwise_fma(x2, C5, C4);
    pl = __builtin_elementwise_fma(x2, pl, C3);
    pl = __builtin_elementwise_fma(x2, pl, C2);
    pl = __builtin_elementwise_fma(x2, pl, C1);
    pl = __builtin_elementwise_fma(x2, pl, C0);
    const v4f a    = u * pl;
    const v4f asub = 1.57079632679489662f - a;

    v4f rs;
#pragma unroll
    for (int j = 0; j < 4; ++j)
        rs[j] = __builtin_copysignf(big[j] ? asub[j] : a[j], Hc[j]);
    const v4f siv = 0.63661977236758134f * rs;

    float res[4];
#pragma unroll
    for (int j = 0; j < 4; ++j)
        res[j] = (siv[j] == siv[j]) ? siv[j] : 0.0f;   // remove_nan

    *(float4*)(out + (size_t)b * (H_ * W_) + h * W_ + w) =
        make_float4(res[0], res[1], res[2], res[3]);
}

extern "C" void kernel_launch(void* const* d_in, const int* in_sizes, int n_in,
                              void* d_out, int out_size, void* d_ws, size_t ws_size,
                              hipStream_t stream) {
    const float* x = (const float*)d_in[0];
    float* out = (float*)d_out;
    dim3 grid(H_, B_);
    dim3 block(384);
    ShapeIndex_kernel<<<grid, block, 0, stream>>>(x, out);
}